// Round 1
// baseline (15561.588 us; speedup 1.0000x reference)
//
#include <hip/hip_runtime.h>

// MovieNet: 6 proj GEMMs(+tanh+dot epilogue) -> 21 softmax -> enc LSTM (persistent)
// -> ctx -> dec xg GEMM -> dec LSTM (persistent) -> MLP.
// All heavy GEMMs: bf16 MFMA 16x16x32, fp32 accumulate.

#define B_ 32
#define T_ 512
#define H_ 512
#define M_ (B_*T_)   // 16384
#define NWG 64       // persistent LSTM workgroups (each owns 8 hidden units)

typedef __attribute__((ext_vector_type(8))) short bf16x8;
typedef __attribute__((ext_vector_type(4))) float f32x4;

__device__ inline unsigned short f2bf(float f){
  unsigned int u = __builtin_bit_cast(unsigned int, f);
  u += 0x7fffu + ((u>>16)&1u);      // round-to-nearest-even
  return (unsigned short)(u>>16);
}
__device__ inline float bf2f(unsigned short s){
  unsigned int u = ((unsigned int)s)<<16;
  return __builtin_bit_cast(float, u);
}
__device__ inline float tanh_f(float x){
  float ax = fabsf(x);
  if (ax > 12.f) return (x>0.f)?1.f:-1.f;
  float e = __expf(2.f*ax);
  float t = (e-1.f)/(e+1.f);
  return (x>=0.f)? t : -t;
}
__device__ inline float sigm(float x){ return 1.f/(1.f+__expf(-x)); }

// ---------------------------------------------------------------------------
// Tiled bf16 GEMM, 128x128 tile, BK=32, 256 thr (4 waves, 2x2 of 64x64).
// MODE 0: A=fp32 features, epilogue tanh(acc+bias) then dot with w1/w2/w3,
//         atomicAdd row partials into s1/s2/s3 (t_x never materialized).
// MODE 1: A=bf16, epilogue acc+bias -> bf16 store.
// MODE 2: A=bf16, epilogue relu(acc+bias) -> bf16 store.
template<int MODE>
__global__ __launch_bounds__(256)
void gemm_k(const void* __restrict__ Ap, const float* __restrict__ Bw,
            const float* __restrict__ bias, int K,
            float* __restrict__ s1, float* __restrict__ s2, float* __restrict__ s3,
            const float* __restrict__ w1, const float* __restrict__ w2, const float* __restrict__ w3,
            unsigned short* __restrict__ outp, int ldout)
{
  __shared__ short As[128*40];   // +8 pad elems per row: conflict-free b128 reads
  __shared__ short Bs[128*40];
  const int tid = threadIdx.x;
  const int cb = blockIdx.x, rb = blockIdx.y;
  const int lane = tid & 63, wv = tid >> 6;
  const int vm = wv & 1, vn = wv >> 1;
  const int r = tid >> 1;
  const int c0 = (tid & 1) << 4;

  f32x4 acc[4][4];
  const f32x4 zz = {0.f,0.f,0.f,0.f};
  #pragma unroll
  for (int i=0;i<4;i++)
    #pragma unroll
    for (int j=0;j<4;j++) acc[i][j] = zz;

  union { short s[16]; bf16x8 v[2]; } tmpu;

  for (int kb = 0; kb < K; kb += 32){
    if (MODE == 0){
      const float* A = (const float*)Ap + (size_t)(rb*128 + r)*K + kb + c0;
      #pragma unroll
      for (int q=0;q<4;q++){
        float4 vv = ((const float4*)A)[q];
        tmpu.s[q*4+0]=(short)f2bf(vv.x); tmpu.s[q*4+1]=(short)f2bf(vv.y);
        tmpu.s[q*4+2]=(short)f2bf(vv.z); tmpu.s[q*4+3]=(short)f2bf(vv.w);
      }
      *(bf16x8*)&As[r*40 + c0]   = tmpu.v[0];
      *(bf16x8*)&As[r*40 + c0+8] = tmpu.v[1];
    } else {
      const unsigned short* A = (const unsigned short*)Ap + (size_t)(rb*128 + r)*K + kb + c0;
      uint4 u0 = ((const uint4*)A)[0];
      uint4 u1 = ((const uint4*)A)[1];
      *(uint4*)&As[r*40 + c0]   = u0;
      *(uint4*)&As[r*40 + c0+8] = u1;
    }
    {
      const float* Bp = Bw + (size_t)(cb*128 + r)*K + kb + c0;
      #pragma unroll
      for (int q=0;q<4;q++){
        float4 vv = ((const float4*)Bp)[q];
        tmpu.s[q*4+0]=(short)f2bf(vv.x); tmpu.s[q*4+1]=(short)f2bf(vv.y);
        tmpu.s[q*4+2]=(short)f2bf(vv.z); tmpu.s[q*4+3]=(short)f2bf(vv.w);
      }
      *(bf16x8*)&Bs[r*40 + c0]   = tmpu.v[0];
      *(bf16x8*)&Bs[r*40 + c0+8] = tmpu.v[1];
    }
    __syncthreads();
    bf16x8 af[4], bfr[4];
    const int fo = ((lane>>4)<<3);
    #pragma unroll
    for (int i=0;i<4;i++) af[i]  = *(const bf16x8*)&As[(vm*64 + i*16 + (lane&15))*40 + fo];
    #pragma unroll
    for (int i=0;i<4;i++) bfr[i] = *(const bf16x8*)&Bs[(vn*64 + i*16 + (lane&15))*40 + fo];
    #pragma unroll
    for (int mt=0;mt<4;mt++)
      #pragma unroll
      for (int nt=0;nt<4;nt++)
        acc[mt][nt] = __builtin_amdgcn_mfma_f32_16x16x32_bf16(af[mt], bfr[nt], acc[mt][nt], 0,0,0);
    __syncthreads();
  }

  const int rowbase = rb*128 + vm*64;
  const int colbase = cb*128 + vn*64;
  if (MODE == 0){
    float bv[4], w1v[4], w2v[4], w3v[4];
    #pragma unroll
    for (int nt=0;nt<4;nt++){
      int c = colbase + nt*16 + (lane&15);
      bv[nt]=bias[c]; w1v[nt]=w1[c]; w2v[nt]=w2[c]; w3v[nt]=w3[c];
    }
    #pragma unroll
    for (int mt=0;mt<4;mt++){
      #pragma unroll
      for (int rr=0;rr<4;rr++){
        float d1=0.f,d2=0.f,d3=0.f;
        #pragma unroll
        for (int nt=0;nt<4;nt++){
          float tv = tanh_f(acc[mt][nt][rr] + bv[nt]);
          d1 = fmaf(tv, w1v[nt], d1);
          d2 = fmaf(tv, w2v[nt], d2);
          d3 = fmaf(tv, w3v[nt], d3);
        }
        #pragma unroll
        for (int m=1;m<16;m<<=1){
          d1 += __shfl_xor(d1, m);
          d2 += __shfl_xor(d2, m);
          d3 += __shfl_xor(d3, m);
        }
        if ((lane & 15) == 0){
          int row = rowbase + mt*16 + ((lane>>4)<<2) + rr;
          atomicAdd(&s1[row], d1);
          atomicAdd(&s2[row], d2);
          atomicAdd(&s3[row], d3);
        }
      }
    }
  } else {
    #pragma unroll
    for (int mt=0;mt<4;mt++){
      #pragma unroll
      for (int nt=0;nt<4;nt++){
        int c = colbase + nt*16 + (lane&15);
        float bb = bias[c];
        #pragma unroll
        for (int rr=0;rr<4;rr++){
          int row = rowbase + mt*16 + ((lane>>4)<<2) + rr;
          float vv = acc[mt][nt][rr] + bb;
          if (MODE == 2) vv = fmaxf(vv, 0.f);
          outp[(size_t)row*ldout + c] = f2bf(vv);
        }
      }
    }
  }
}

// ---------------------------------------------------------------------------
// 21 softmaxes over T per batch. Scalar biases omitted (softmax shift-invariant).
__global__ __launch_bounds__(256)
void softmax_k(const float* __restrict__ sacc, float* __restrict__ sm)
{
  const int u = blockIdx.x % 21, b = blockIdx.x / 21;
  const int tid = threadIdx.x;
  __shared__ float red[4], red2[4];
  float v0, v1;
  if (u < 15){
    const int pa[15] = {0,0,0,0,0,1,1,1,1,2,2,2,3,3,4};
    const int pb[15] = {2,1,3,4,5,2,3,4,5,3,4,5,4,5,5};
    const float* A  = sacc + (size_t)(pa[u]*3+0)*M_ + b*T_;
    const float* Bq = sacc + (size_t)(pb[u]*3+1)*M_ + b*T_;
    v0 = A[tid] + Bq[tid]; v1 = A[tid+256] + Bq[tid+256];
  } else {
    const float* A = sacc + (size_t)((u-15)*3+2)*M_ + b*T_;
    v0 = A[tid]; v1 = A[tid+256];
  }
  float mx = fmaxf(v0,v1);
  #pragma unroll
  for (int d=1;d<64;d<<=1) mx = fmaxf(mx, __shfl_xor(mx,d));
  if ((tid&63)==0) red[tid>>6]=mx;
  __syncthreads();
  mx = fmaxf(fmaxf(red[0],red[1]),fmaxf(red[2],red[3]));
  float e0 = __expf(v0-mx), e1 = __expf(v1-mx);
  float s = e0+e1;
  #pragma unroll
  for (int d=1;d<64;d<<=1) s += __shfl_xor(s,d);
  if ((tid&63)==0) red2[tid>>6]=s;
  __syncthreads();
  s = red2[0]+red2[1]+red2[2]+red2[3];
  float inv = 1.f/s;
  float* o = sm + (size_t)u*M_ + b*T_;
  o[tid] = e0*inv; o[tid+256] = e1*inv;
}

// ---------------------------------------------------------------------------
// Seed the LSTM exchange buffers: dec h0, enc enc_in[t=0] slots, const "1" slot.
__global__ __launch_bounds__(256)
void init2_k(const float* __restrict__ smu, const float* __restrict__ dh0,
             unsigned short* __restrict__ hbe, unsigned short* __restrict__ hbd)
{
  int gid = blockIdx.x*256 + threadIdx.x;  // 0..16383
  { int b = gid >> 9, j = gid & 511; hbd[b*544 + j] = f2bf(dh0[j]); }
  if (gid < 32*6){
    int b = gid / 6, k = gid % 6;
    // enc_in[b,0,k] = uni_{k//512}[b, k%512] -> unit 0 for k<6
    hbe[b*544 + 512 + k] = f2bf(smu[b*T_ + k]);
  }
  if (gid < 64){
    int b = gid & 31, bufi = gid >> 5;
    hbe[bufi*(32*544) + b*544 + 518] = 0x3F80;  // 1.0 (bias lane)
  }
}

// ---------------------------------------------------------------------------
// Persistent LSTM. 64 WGs x 128 thr. WG w owns hidden [w*8, w*8+8).
// Gates for all 32 batches via MFMA: A = [h(512); enc_in(6); 1; pad] (K=544),
// B = W_hh rows (+Wih cols +bias col for enc), resident in VGPR fragments.
// h exchanged via double-buffered global hbuf with per-WG step flags,
// all cross-WG traffic as AGENT-scope atomics (XCD-coherence safe).
template<bool ENC>
__global__ __launch_bounds__(128, 1)
void lstm_k(const float* __restrict__ Whh, const float* __restrict__ Wih,
            const float* __restrict__ bvec, const float* __restrict__ smu,
            const unsigned short* __restrict__ xg, const float* __restrict__ c0v,
            unsigned short* hbuf, int* flags, unsigned short* __restrict__ outbuf)
{
  const int w = blockIdx.x, tid = threadIdx.x;
  const int lane = tid & 63, v = tid >> 6;

  bf16x8 bfrag[17];
  {
    const int n = lane & 15;
    const int R = (n&3)*512 + w*8 + v*4 + (n>>2);  // gate (n&3), hidden w*8+v*4+(n>>2)
    const int kq0 = (lane>>4)<<3;
    for (int ks=0; ks<17; ks++){
      union { short s[8]; bf16x8 vv; } bu;
      for (int j=0;j<8;j++){
        int k = ks*32 + kq0 + j;
        float val = 0.f;
        if (k < 512) val = Whh[(size_t)R*512 + k];
        else if (ENC){
          if (k < 518) val = Wih[R*6 + (k-512)];
          else if (k == 518) val = bvec[R];
        }
        bu.s[j] = (short)f2bf(val);
      }
      bfrag[ks] = bu.vv;
    }
  }
  const int b = tid & 31, u = tid >> 5;
  const int j0 = w*8 + u*2;
  float c0 = ENC ? 0.f : c0v[j0];
  float c1 = ENC ? 0.f : c0v[j0+1];
  __shared__ float gl[32*33];
  const int m = lane & 15;
  const int kq = (lane>>4)<<3;

  for (int t = 1; t <= 512; t++){
    float xv0[4], xv1[4];
    if (!ENC){  // prefetch precomputed xg (independent of h -> hides latency)
      const size_t bx = ((size_t)(b*512 + (t-1)))*2048 + w*8;
      #pragma unroll
      for (int g=0; g<4; g++){
        xv0[g] = bf2f(xg[bx + g*512 + u*2]);
        xv1[g] = bf2f(xg[bx + g*512 + u*2 + 1]);
      }
    }
    {
      const int want = t-1;
      while (true){
        int f = __hip_atomic_load(&flags[lane & (NWG-1)], __ATOMIC_ACQUIRE, __HIP_MEMORY_SCOPE_AGENT);
        if (__all(f >= want)) break;
        __builtin_amdgcn_s_sleep(1);
      }
    }
    const unsigned short* hb = hbuf + ((t-1)&1)*(32*544);
    f32x4 acc0 = {0.f,0.f,0.f,0.f}, acc1 = {0.f,0.f,0.f,0.f};
    {
      bf16x8 af0[17], af1[17];
      #pragma unroll
      for (int ks=0; ks<17; ks++){
        const unsigned long long* p0 = (const unsigned long long*)(hb + (size_t)m*544 + ks*32 + kq);
        const unsigned long long* p1 = (const unsigned long long*)(hb + (size_t)(m+16)*544 + ks*32 + kq);
        union { unsigned long long q[2]; bf16x8 vv; } a0, a1;
        a0.q[0] = __hip_atomic_load(p0,   __ATOMIC_RELAXED, __HIP_MEMORY_SCOPE_AGENT);
        a0.q[1] = __hip_atomic_load(p0+1, __ATOMIC_RELAXED, __HIP_MEMORY_SCOPE_AGENT);
        a1.q[0] = __hip_atomic_load(p1,   __ATOMIC_RELAXED, __HIP_MEMORY_SCOPE_AGENT);
        a1.q[1] = __hip_atomic_load(p1+1, __ATOMIC_RELAXED, __HIP_MEMORY_SCOPE_AGENT);
        af0[ks] = a0.vv; af1[ks] = a1.vv;
      }
      #pragma unroll
      for (int ks=0; ks<17; ks++){
        acc0 = __builtin_amdgcn_mfma_f32_16x16x32_bf16(af0[ks], bfrag[ks], acc0, 0,0,0);
        acc1 = __builtin_amdgcn_mfma_f32_16x16x32_bf16(af1[ks], bfrag[ks], acc1, 0,0,0);
      }
    }
    {
      const int col = v*16 + (lane&15);
      const int qb = ((lane>>4)<<2);
      #pragma unroll
      for (int rr=0;rr<4;rr++) gl[col*33 + qb + rr] = acc0[rr];
      #pragma unroll
      for (int rr=0;rr<4;rr++) gl[col*33 + 16 + qb + rr] = acc1[rr];
    }
    __syncthreads();
    unsigned int hw;
    {
      float hn[2];
      #pragma unroll
      for (int e=0;e<2;e++){
        const int jl = u*2 + e;
        const int colb = (jl>>2)*16 + (jl&3)*4;
        float gi = gl[(colb+0)*33 + b];
        float gf = gl[(colb+1)*33 + b];
        float gg = gl[(colb+2)*33 + b];
        float go = gl[(colb+3)*33 + b];
        if (!ENC){
          gi += e?xv1[0]:xv0[0]; gf += e?xv1[1]:xv0[1];
          gg += e?xv1[2]:xv0[2]; go += e?xv1[3]:xv0[3];
        }
        float& cc = e ? c1 : c0;
        cc = sigm(gf)*cc + sigm(gi)*tanh_f(gg);
        hn[e] = sigm(go)*tanh_f(cc);
      }
      hw = (unsigned int)f2bf(hn[0]) | ((unsigned int)f2bf(hn[1])<<16);
    }
    unsigned short* hbw = hbuf + (t&1)*(32*544);
    __hip_atomic_store((unsigned int*)(hbw + b*544 + j0), hw, __ATOMIC_RELAXED, __HIP_MEMORY_SCOPE_AGENT);
    *(unsigned int*)(outbuf + ((size_t)(b*512 + (t-1)))*512 + j0) = hw;
    if (ENC && w < 32 && tid < 3 && t < 512){
      // stage enc_in for step t+1 into the buffer being published this step
      int q0 = 6*t + tid*2, q1 = q0 + 1;
      unsigned int ev = (unsigned int)f2bf(smu[(size_t)(q0>>9)*M_ + w*T_ + (q0&511)])
                      | ((unsigned int)f2bf(smu[(size_t)(q1>>9)*M_ + w*T_ + (q1&511)])<<16);
      __hip_atomic_store((unsigned int*)(hbw + w*544 + 512 + tid*2), ev, __ATOMIC_RELAXED, __HIP_MEMORY_SCOPE_AGENT);
    }
    __threadfence();
    __syncthreads();
    if (tid == 0) __hip_atomic_store(&flags[w], t, __ATOMIC_RELEASE, __HIP_MEMORY_SCOPE_AGENT);
  }
}

// ---------------------------------------------------------------------------
// ctx[b,t,:] = sum_{i<15, t-i>=0} attn[b,t,i]*enc_out[b,t-i,:], attn via interleave gather.
__global__ __launch_bounds__(256)
void ctx_k(const float* __restrict__ smatt, const unsigned short* __restrict__ enc_out,
           unsigned short* __restrict__ ctx)
{
  const int bt = blockIdx.x;
  const int b = bt >> 9, t = bt & 511;
  __shared__ float a[15];
  const int tid = threadIdx.x;
  if (tid < 15){
    int q = 15*t + tid;
    a[tid] = smatt[(size_t)(q>>9)*M_ + b*T_ + (q&511)];
  }
  __syncthreads();
  const int j0 = tid*2;
  float s0=0.f, s1=0.f;
  for (int i=0;i<15;i++){
    int tau = t - i;
    if (tau < 0) break;
    unsigned int pr = *(const unsigned int*)(enc_out + ((size_t)(b*512+tau))*512 + j0);
    float wv = a[i];
    s0 = fmaf(wv, bf2f((unsigned short)(pr & 0xffff)), s0);
    s1 = fmaf(wv, bf2f((unsigned short)(pr >> 16)), s1);
  }
  unsigned int o = (unsigned int)f2bf(s0) | ((unsigned int)f2bf(s1)<<16);
  *(unsigned int*)(ctx + (size_t)bt*512 + j0) = o;
}

// ---------------------------------------------------------------------------
// out = hid @ W2.T + b2  (N=7 skinny). One wave per row.
__global__ __launch_bounds__(256)
void out_k(const unsigned short* __restrict__ hid, const float* __restrict__ W2,
           const float* __restrict__ b2, float* __restrict__ out)
{
  __shared__ float w2s[7*512];
  const int tid = threadIdx.x;
  for (int i = tid; i < 7*512; i += 256) w2s[i] = W2[i];
  __syncthreads();
  const int wv = tid>>6, lane = tid&63;
  const int mrow = blockIdx.x*4 + wv;
  float hv[8];
  {
    const uint4 uu = *(const uint4*)(hid + (size_t)mrow*512 + lane*8);
    const unsigned int q[4] = {uu.x, uu.y, uu.z, uu.w};
    #pragma unroll
    for (int i=0;i<4;i++){
      hv[i*2]   = bf2f((unsigned short)(q[i] & 0xffff));
      hv[i*2+1] = bf2f((unsigned short)(q[i] >> 16));
    }
  }
  float s[7];
  #pragma unroll
  for (int o=0;o<7;o++){
    float acc = 0.f;
    #pragma unroll
    for (int j=0;j<8;j++) acc = fmaf(hv[j], w2s[o*512 + lane*8 + j], acc);
    #pragma unroll
    for (int d=1; d<64; d<<=1) acc += __shfl_xor(acc, d);
    s[o] = acc;
  }
  if (lane == 0){
    #pragma unroll
    for (int o=0;o<7;o++) out[(size_t)mrow*7 + o] = s[o] + b2[o];
  }
}

// ---------------------------------------------------------------------------
// Workspace layout (needs ~136 MiB)
#define OFF_SACC   0ULL          // 18*16384*4 = 1179648
#define OFF_SM     2097152ULL    // 21*16384*4 = 1376256
#define OFF_FLAGS  3670016ULL    // enc:+0, dec:+256
#define OFF_HBUF_E 4194304ULL    // 2*32*544*2 = 69632
#define OFF_HBUF_D 4325376ULL    // 69632
#define OFF_ENCOUT 5242880ULL    // 16 MiB bf16
#define OFF_CTX    23068672ULL   // 16 MiB bf16
#define OFF_XG     41943040ULL   // 64 MiB bf16 (16384x2048)
#define OFF_DECOUT 109051904ULL  // 16 MiB bf16
#define OFF_HID    125829120ULL  // 16 MiB bf16

extern "C" void kernel_launch(void* const* d_in, const int* in_sizes, int n_in,
                              void* d_out, int out_size, void* d_ws, size_t ws_size,
                              hipStream_t stream)
{
  const float* face  = (const float*)d_in[1];
  const float* audio = (const float*)d_in[2];
  const float* desc  = (const float*)d_in[3];
  const float* sit   = (const float*)d_in[4];
  const float* scene = (const float*)d_in[5];
  const float* text  = (const float*)d_in[6];
  const float* Wt  = (const float*)d_in[8];  const float* bt  = (const float*)d_in[9];
  const float* Wf  = (const float*)d_in[10]; const float* bfc = (const float*)d_in[11];
  const float* Wa  = (const float*)d_in[12]; const float* ba  = (const float*)d_in[13];
  const float* Wsc = (const float*)d_in[14]; const float* bsc = (const float*)d_in[15];
  const float* Wd  = (const float*)d_in[16]; const float* bd  = (const float*)d_in[17];
  const float* Wsi = (const float*)d_in[18]; const float* bsi = (const float*)d_in[19];
  const float* w_att = (const float*)d_in[20];
  const float* w_ut = (const float*)d_in[22];
  const float* w_uf = (const float*)d_in[24];
  const float* w_ua = (const float*)d_in[26];
  const float* enc_Wih = (const float*)d_in[28];
  const float* enc_Whh = (const float*)d_in[29];
  const float* enc_b   = (const float*)d_in[30];
  const float* dec_Wih = (const float*)d_in[31];
  const float* dec_Whh = (const float*)d_in[32];
  const float* dec_b   = (const float*)d_in[33];
  const float* dec_h0  = (const float*)d_in[34];
  const float* dec_c0  = (const float*)d_in[35];
  const float* W1 = (const float*)d_in[36]; const float* b1 = (const float*)d_in[37];
  const float* W2 = (const float*)d_in[38]; const float* b2 = (const float*)d_in[39];
  float* outp = (float*)d_out;

  char* ws = (char*)d_ws;
  float* sacc = (float*)(ws + OFF_SACC);
  float* sm   = (float*)(ws + OFF_SM);
  int* flagsE = (int*)(ws + OFF_FLAGS);
  int* flagsD = (int*)(ws + OFF_FLAGS + 256);
  unsigned short* hbe = (unsigned short*)(ws + OFF_HBUF_E);
  unsigned short* hbd = (unsigned short*)(ws + OFF_HBUF_D);
  unsigned short* enc_out = (unsigned short*)(ws + OFF_ENCOUT);
  unsigned short* ctx = (unsigned short*)(ws + OFF_CTX);
  unsigned short* xg  = (unsigned short*)(ws + OFF_XG);
  unsigned short* dec_out = (unsigned short*)(ws + OFF_DECOUT);
  unsigned short* hid = (unsigned short*)(ws + OFF_HID);
  const float* smu = sm + 15*M_;   // uni softmaxes

  hipMemsetAsync(ws + OFF_SACC, 0, 18*M_*4, stream);
  hipMemsetAsync(ws + OFF_FLAGS, 0, (size_t)(OFF_HBUF_D + 69632 - OFF_FLAGS), stream);

  dim3 blk(256);
  dim3 g1(4,128);
  const float* w1p = w_att; const float* w2p = w_att + 512;
  // feature order: 0=text 1=face 2=audio 3=scene 4=desc 5=sit
  gemm_k<0><<<g1, blk, 0, stream>>>(text,  Wt,  bt,  768,  sacc+0*M_,  sacc+1*M_,  sacc+2*M_,  w1p, w2p, w_ut, nullptr, 0);
  gemm_k<0><<<g1, blk, 0, stream>>>(face,  Wf,  bfc, 512,  sacc+3*M_,  sacc+4*M_,  sacc+5*M_,  w1p, w2p, w_uf, nullptr, 0);
  gemm_k<0><<<g1, blk, 0, stream>>>(audio, Wa,  ba,  128,  sacc+6*M_,  sacc+7*M_,  sacc+8*M_,  w1p, w2p, w_ua, nullptr, 0);
  gemm_k<0><<<g1, blk, 0, stream>>>(scene, Wsc, bsc, 2048, sacc+9*M_,  sacc+10*M_, sacc+11*M_, w1p, w2p, w_ut, nullptr, 0);
  gemm_k<0><<<g1, blk, 0, stream>>>(desc,  Wd,  bd,  768,  sacc+12*M_, sacc+13*M_, sacc+14*M_, w1p, w2p, w_uf, nullptr, 0);
  gemm_k<0><<<g1, blk, 0, stream>>>(sit,   Wsi, bsi, 768,  sacc+15*M_, sacc+16*M_, sacc+17*M_, w1p, w2p, w_ua, nullptr, 0);
  softmax_k<<<dim3(21*32), blk, 0, stream>>>(sacc, sm);
  init2_k<<<dim3(64), blk, 0, stream>>>(smu, dec_h0, hbe, hbd);
  lstm_k<true><<<dim3(NWG), dim3(128), 0, stream>>>(enc_Whh, enc_Wih, enc_b, smu,
                                                    nullptr, nullptr, hbe, flagsE, enc_out);
  ctx_k<<<dim3(M_), blk, 0, stream>>>(sm, enc_out, ctx);
  gemm_k<1><<<dim3(16,128), blk, 0, stream>>>(ctx, dec_Wih, dec_b, 512,
      nullptr,nullptr,nullptr,nullptr,nullptr,nullptr, xg, 2048);
  lstm_k<false><<<dim3(NWG), dim3(128), 0, stream>>>(dec_Whh, nullptr, nullptr, nullptr,
                                                     xg, dec_c0, hbd, flagsD, dec_out);
  gemm_k<2><<<dim3(4,128), blk, 0, stream>>>(dec_out, W1, b1, 512,
      nullptr,nullptr,nullptr,nullptr,nullptr,nullptr, hid, 512);
  out_k<<<dim3(M_/4), blk, 0, stream>>>(hid, W2, b2, outp);
  (void)in_sizes; (void)n_in; (void)out_size; (void)ws_size;
}

// Round 2
// 9971.897 us; speedup vs baseline: 1.5605x; 1.5605x over previous
//
#include <hip/hip_runtime.h>

// MovieNet: 6 proj GEMMs(+tanh+dot epilogue) -> 21 softmax -> enc LSTM (persistent)
// -> ctx -> dec xg GEMM -> dec LSTM (persistent) -> MLP.
// All heavy GEMMs: bf16 MFMA 16x16x32, fp32 accumulate.
// R2: LSTM handoff uses RELAXED agent atomics + explicit s_waitcnt vmcnt(0)
//     instead of acquire/release fences (which emit buffer_inv/buffer_wbl2 =
//     full per-XCD L2 invalidate/writeback per poll -> 345 MB FETCH, 15us/step).

#define B_ 32
#define T_ 512
#define H_ 512
#define M_ (B_*T_)   // 16384
#define NWG 64       // persistent LSTM workgroups (each owns 8 hidden units)

typedef __attribute__((ext_vector_type(8))) short bf16x8;
typedef __attribute__((ext_vector_type(4))) float f32x4;

__device__ inline unsigned short f2bf(float f){
  unsigned int u = __builtin_bit_cast(unsigned int, f);
  u += 0x7fffu + ((u>>16)&1u);      // round-to-nearest-even
  return (unsigned short)(u>>16);
}
__device__ inline float bf2f(unsigned short s){
  unsigned int u = ((unsigned int)s)<<16;
  return __builtin_bit_cast(float, u);
}
__device__ inline float tanh_f(float x){
  float ax = fabsf(x);
  if (ax > 12.f) return (x>0.f)?1.f:-1.f;
  float e = __expf(2.f*ax);
  float t = (e-1.f)/(e+1.f);
  return (x>=0.f)? t : -t;
}
__device__ inline float sigm(float x){ return 1.f/(1.f+__expf(-x)); }

// ---------------------------------------------------------------------------
// Tiled bf16 GEMM, 128x128 tile, BK=32, 256 thr (4 waves, 2x2 of 64x64).
// MODE 0: A=fp32 features, epilogue tanh(acc+bias) then dot with w1/w2/w3,
//         atomicAdd row partials into s1/s2/s3 (t_x never materialized).
// MODE 1: A=bf16, epilogue acc+bias -> bf16 store.
// MODE 2: A=bf16, epilogue relu(acc+bias) -> bf16 store.
template<int MODE>
__global__ __launch_bounds__(256)
void gemm_k(const void* __restrict__ Ap, const float* __restrict__ Bw,
            const float* __restrict__ bias, int K,
            float* __restrict__ s1, float* __restrict__ s2, float* __restrict__ s3,
            const float* __restrict__ w1, const float* __restrict__ w2, const float* __restrict__ w3,
            unsigned short* __restrict__ outp, int ldout)
{
  __shared__ short As[128*40];   // +8 pad elems per row: conflict-free b128 reads
  __shared__ short Bs[128*40];
  const int tid = threadIdx.x;
  const int cb = blockIdx.x, rb = blockIdx.y;
  const int lane = tid & 63, wv = tid >> 6;
  const int vm = wv & 1, vn = wv >> 1;
  const int r = tid >> 1;
  const int c0 = (tid & 1) << 4;

  f32x4 acc[4][4];
  const f32x4 zz = {0.f,0.f,0.f,0.f};
  #pragma unroll
  for (int i=0;i<4;i++)
    #pragma unroll
    for (int j=0;j<4;j++) acc[i][j] = zz;

  union { short s[16]; bf16x8 v[2]; } tmpu;

  for (int kb = 0; kb < K; kb += 32){
    if (MODE == 0){
      const float* A = (const float*)Ap + (size_t)(rb*128 + r)*K + kb + c0;
      #pragma unroll
      for (int q=0;q<4;q++){
        float4 vv = ((const float4*)A)[q];
        tmpu.s[q*4+0]=(short)f2bf(vv.x); tmpu.s[q*4+1]=(short)f2bf(vv.y);
        tmpu.s[q*4+2]=(short)f2bf(vv.z); tmpu.s[q*4+3]=(short)f2bf(vv.w);
      }
      *(bf16x8*)&As[r*40 + c0]   = tmpu.v[0];
      *(bf16x8*)&As[r*40 + c0+8] = tmpu.v[1];
    } else {
      const unsigned short* A = (const unsigned short*)Ap + (size_t)(rb*128 + r)*K + kb + c0;
      uint4 u0 = ((const uint4*)A)[0];
      uint4 u1 = ((const uint4*)A)[1];
      *(uint4*)&As[r*40 + c0]   = u0;
      *(uint4*)&As[r*40 + c0+8] = u1;
    }
    {
      const float* Bp = Bw + (size_t)(cb*128 + r)*K + kb + c0;
      #pragma unroll
      for (int q=0;q<4;q++){
        float4 vv = ((const float4*)Bp)[q];
        tmpu.s[q*4+0]=(short)f2bf(vv.x); tmpu.s[q*4+1]=(short)f2bf(vv.y);
        tmpu.s[q*4+2]=(short)f2bf(vv.z); tmpu.s[q*4+3]=(short)f2bf(vv.w);
      }
      *(bf16x8*)&Bs[r*40 + c0]   = tmpu.v[0];
      *(bf16x8*)&Bs[r*40 + c0+8] = tmpu.v[1];
    }
    __syncthreads();
    bf16x8 af[4], bfr[4];
    const int fo = ((lane>>4)<<3);
    #pragma unroll
    for (int i=0;i<4;i++) af[i]  = *(const bf16x8*)&As[(vm*64 + i*16 + (lane&15))*40 + fo];
    #pragma unroll
    for (int i=0;i<4;i++) bfr[i] = *(const bf16x8*)&Bs[(vn*64 + i*16 + (lane&15))*40 + fo];
    #pragma unroll
    for (int mt=0;mt<4;mt++)
      #pragma unroll
      for (int nt=0;nt<4;nt++)
        acc[mt][nt] = __builtin_amdgcn_mfma_f32_16x16x32_bf16(af[mt], bfr[nt], acc[mt][nt], 0,0,0);
    __syncthreads();
  }

  const int rowbase = rb*128 + vm*64;
  const int colbase = cb*128 + vn*64;
  if (MODE == 0){
    float bv[4], w1v[4], w2v[4], w3v[4];
    #pragma unroll
    for (int nt=0;nt<4;nt++){
      int c = colbase + nt*16 + (lane&15);
      bv[nt]=bias[c]; w1v[nt]=w1[c]; w2v[nt]=w2[c]; w3v[nt]=w3[c];
    }
    #pragma unroll
    for (int mt=0;mt<4;mt++){
      #pragma unroll
      for (int rr=0;rr<4;rr++){
        float d1=0.f,d2=0.f,d3=0.f;
        #pragma unroll
        for (int nt=0;nt<4;nt++){
          float tv = tanh_f(acc[mt][nt][rr] + bv[nt]);
          d1 = fmaf(tv, w1v[nt], d1);
          d2 = fmaf(tv, w2v[nt], d2);
          d3 = fmaf(tv, w3v[nt], d3);
        }
        #pragma unroll
        for (int m=1;m<16;m<<=1){
          d1 += __shfl_xor(d1, m);
          d2 += __shfl_xor(d2, m);
          d3 += __shfl_xor(d3, m);
        }
        if ((lane & 15) == 0){
          int row = rowbase + mt*16 + ((lane>>4)<<2) + rr;
          atomicAdd(&s1[row], d1);
          atomicAdd(&s2[row], d2);
          atomicAdd(&s3[row], d3);
        }
      }
    }
  } else {
    #pragma unroll
    for (int mt=0;mt<4;mt++){
      #pragma unroll
      for (int nt=0;nt<4;nt++){
        int c = colbase + nt*16 + (lane&15);
        float bb = bias[c];
        #pragma unroll
        for (int rr=0;rr<4;rr++){
          int row = rowbase + mt*16 + ((lane>>4)<<2) + rr;
          float vv = acc[mt][nt][rr] + bb;
          if (MODE == 2) vv = fmaxf(vv, 0.f);
          outp[(size_t)row*ldout + c] = f2bf(vv);
        }
      }
    }
  }
}

// ---------------------------------------------------------------------------
// 21 softmaxes over T per batch. Scalar biases omitted (softmax shift-invariant).
__global__ __launch_bounds__(256)
void softmax_k(const float* __restrict__ sacc, float* __restrict__ sm)
{
  const int u = blockIdx.x % 21, b = blockIdx.x / 21;
  const int tid = threadIdx.x;
  __shared__ float red[4], red2[4];
  float v0, v1;
  if (u < 15){
    const int pa[15] = {0,0,0,0,0,1,1,1,1,2,2,2,3,3,4};
    const int pb[15] = {2,1,3,4,5,2,3,4,5,3,4,5,4,5,5};
    const float* A  = sacc + (size_t)(pa[u]*3+0)*M_ + b*T_;
    const float* Bq = sacc + (size_t)(pb[u]*3+1)*M_ + b*T_;
    v0 = A[tid] + Bq[tid]; v1 = A[tid+256] + Bq[tid+256];
  } else {
    const float* A = sacc + (size_t)((u-15)*3+2)*M_ + b*T_;
    v0 = A[tid]; v1 = A[tid+256];
  }
  float mx = fmaxf(v0,v1);
  #pragma unroll
  for (int d=1;d<64;d<<=1) mx = fmaxf(mx, __shfl_xor(mx,d));
  if ((tid&63)==0) red[tid>>6]=mx;
  __syncthreads();
  mx = fmaxf(fmaxf(red[0],red[1]),fmaxf(red[2],red[3]));
  float e0 = __expf(v0-mx), e1 = __expf(v1-mx);
  float s = e0+e1;
  #pragma unroll
  for (int d=1;d<64;d<<=1) s += __shfl_xor(s,d);
  if ((tid&63)==0) red2[tid>>6]=s;
  __syncthreads();
  s = red2[0]+red2[1]+red2[2]+red2[3];
  float inv = 1.f/s;
  float* o = sm + (size_t)u*M_ + b*T_;
  o[tid] = e0*inv; o[tid+256] = e1*inv;
}

// ---------------------------------------------------------------------------
// Seed the LSTM exchange buffers: dec h0, enc enc_in[t=0] slots, const "1" slot.
__global__ __launch_bounds__(256)
void init2_k(const float* __restrict__ smu, const float* __restrict__ dh0,
             unsigned short* __restrict__ hbe, unsigned short* __restrict__ hbd)
{
  int gid = blockIdx.x*256 + threadIdx.x;  // 0..16383
  { int b = gid >> 9, j = gid & 511; hbd[b*544 + j] = f2bf(dh0[j]); }
  if (gid < 32*6){
    int b = gid / 6, k = gid % 6;
    // enc_in[b,0,k] = uni_{k//512}[b, k%512] -> unit 0 for k<6
    hbe[b*544 + 512 + k] = f2bf(smu[b*T_ + k]);
  }
  if (gid < 64){
    int b = gid & 31, bufi = gid >> 5;
    hbe[bufi*(32*544) + b*544 + 518] = 0x3F80;  // 1.0 (bias lane)
  }
}

// ---------------------------------------------------------------------------
// Persistent LSTM. 64 WGs x 128 thr. WG w owns hidden [w*8, w*8+8).
// Gates for all 32 batches via MFMA: A = [h(512); enc_in(6); 1; pad] (K=544),
// B = W_hh rows (+Wih cols +bias col for enc), resident in VGPR fragments.
// h exchanged via double-buffered global hbuf with per-WG step flags.
// ALL cross-WG traffic: RELAXED agent-scope atomics (sc1, serialized at MALL).
// NO acquire/release fences in the loop: those emit buffer_inv / buffer_wbl2
// (full per-XCD L2 invalidate/writeback) and were the R1 15us/step stall.
// Ordering: producer does s_waitcnt vmcnt(0) (h stores reached MALL) before
// the flag store; consumer's h loads issue only after the poll branch retires.
template<bool ENC>
__global__ __launch_bounds__(128, 1)
void lstm_k(const float* __restrict__ Whh, const float* __restrict__ Wih,
            const float* __restrict__ bvec, const float* __restrict__ smu,
            const unsigned short* __restrict__ xg, const float* __restrict__ c0v,
            unsigned short* hbuf, int* flags, unsigned short* __restrict__ outbuf)
{
  const int w = blockIdx.x, tid = threadIdx.x;
  const int lane = tid & 63, v = tid >> 6;

  bf16x8 bfrag[17];
  {
    const int n = lane & 15;
    const int R = (n&3)*512 + w*8 + v*4 + (n>>2);  // gate (n&3), hidden w*8+v*4+(n>>2)
    const int kq0 = (lane>>4)<<3;
    for (int ks=0; ks<17; ks++){
      union { short s[8]; bf16x8 vv; } bu;
      for (int j=0;j<8;j++){
        int k = ks*32 + kq0 + j;
        float val = 0.f;
        if (k < 512) val = Whh[(size_t)R*512 + k];
        else if (ENC){
          if (k < 518) val = Wih[R*6 + (k-512)];
          else if (k == 518) val = bvec[R];
        }
        bu.s[j] = (short)f2bf(val);
      }
      bfrag[ks] = bu.vv;
    }
  }
  const int b = tid & 31, u = tid >> 5;
  const int j0 = w*8 + u*2;
  float c0 = ENC ? 0.f : c0v[j0];
  float c1 = ENC ? 0.f : c0v[j0+1];
  __shared__ float gl[32*33];
  const int m = lane & 15;
  const int kq = (lane>>4)<<3;

  for (int t = 1; t <= 512; t++){
    float xv0[4], xv1[4];
    if (!ENC){  // prefetch precomputed xg (independent of h -> hides latency)
      const size_t bx = ((size_t)(b*512 + (t-1)))*2048 + w*8;
      #pragma unroll
      for (int g=0; g<4; g++){
        xv0[g] = bf2f(xg[bx + g*512 + u*2]);
        xv1[g] = bf2f(xg[bx + g*512 + u*2 + 1]);
      }
    }
    {
      const int want = t-1;
      while (true){
        int f = __hip_atomic_load(&flags[lane & (NWG-1)], __ATOMIC_RELAXED, __HIP_MEMORY_SCOPE_AGENT);
        if (__all(f >= want)) break;
      }
      __atomic_signal_fence(__ATOMIC_ACQUIRE);  // compiler barrier only
    }
    const unsigned short* hb = hbuf + ((t-1)&1)*(32*544);
    f32x4 acc0 = {0.f,0.f,0.f,0.f}, acc1 = {0.f,0.f,0.f,0.f};
    {
      bf16x8 af0[17], af1[17];
      #pragma unroll
      for (int ks=0; ks<17; ks++){
        const unsigned long long* p0 = (const unsigned long long*)(hb + (size_t)m*544 + ks*32 + kq);
        const unsigned long long* p1 = (const unsigned long long*)(hb + (size_t)(m+16)*544 + ks*32 + kq);
        union { unsigned long long q[2]; bf16x8 vv; } a0, a1;
        a0.q[0] = __hip_atomic_load(p0,   __ATOMIC_RELAXED, __HIP_MEMORY_SCOPE_AGENT);
        a0.q[1] = __hip_atomic_load(p0+1, __ATOMIC_RELAXED, __HIP_MEMORY_SCOPE_AGENT);
        a1.q[0] = __hip_atomic_load(p1,   __ATOMIC_RELAXED, __HIP_MEMORY_SCOPE_AGENT);
        a1.q[1] = __hip_atomic_load(p1+1, __ATOMIC_RELAXED, __HIP_MEMORY_SCOPE_AGENT);
        af0[ks] = a0.vv; af1[ks] = a1.vv;
      }
      #pragma unroll
      for (int ks=0; ks<17; ks++){
        acc0 = __builtin_amdgcn_mfma_f32_16x16x32_bf16(af0[ks], bfrag[ks], acc0, 0,0,0);
        acc1 = __builtin_amdgcn_mfma_f32_16x16x32_bf16(af1[ks], bfrag[ks], acc1, 0,0,0);
      }
    }
    {
      const int col = v*16 + (lane&15);
      const int qb = ((lane>>4)<<2);
      #pragma unroll
      for (int rr=0;rr<4;rr++) gl[col*33 + qb + rr] = acc0[rr];
      #pragma unroll
      for (int rr=0;rr<4;rr++) gl[col*33 + 16 + qb + rr] = acc1[rr];
    }
    __syncthreads();
    unsigned int hw;
    {
      float hn[2];
      #pragma unroll
      for (int e=0;e<2;e++){
        const int jl = u*2 + e;
        const int colb = (jl>>2)*16 + (jl&3)*4;
        float gi = gl[(colb+0)*33 + b];
        float gf = gl[(colb+1)*33 + b];
        float gg = gl[(colb+2)*33 + b];
        float go = gl[(colb+3)*33 + b];
        if (!ENC){
          gi += e?xv1[0]:xv0[0]; gf += e?xv1[1]:xv0[1];
          gg += e?xv1[2]:xv0[2]; go += e?xv1[3]:xv0[3];
        }
        float& cc = e ? c1 : c0;
        cc = sigm(gf)*cc + sigm(gi)*tanh_f(gg);
        hn[e] = sigm(go)*tanh_f(cc);
      }
      hw = (unsigned int)f2bf(hn[0]) | ((unsigned int)f2bf(hn[1])<<16);
    }
    unsigned short* hbw = hbuf + (t&1)*(32*544);
    __hip_atomic_store((unsigned int*)(hbw + b*544 + j0), hw, __ATOMIC_RELAXED, __HIP_MEMORY_SCOPE_AGENT);
    *(unsigned int*)(outbuf + ((size_t)(b*512 + (t-1)))*512 + j0) = hw;
    if (ENC && w < 32 && tid < 3 && t < 512){
      // stage enc_in for step t+1 into the buffer being published this step
      int q0 = 6*t + tid*2, q1 = q0 + 1;
      unsigned int ev = (unsigned int)f2bf(smu[(size_t)(q0>>9)*M_ + w*T_ + (q0&511)])
                      | ((unsigned int)f2bf(smu[(size_t)(q1>>9)*M_ + w*T_ + (q1&511)])<<16);
      __hip_atomic_store((unsigned int*)(hbw + w*544 + 512 + tid*2), ev, __ATOMIC_RELAXED, __HIP_MEMORY_SCOPE_AGENT);
    }
    // Drain this thread's write-through stores to the MALL, then barrier so
    // tid 0's flag publish covers the whole WG. No buffer_wbl2 / buffer_inv.
    asm volatile("s_waitcnt vmcnt(0)" ::: "memory");
    __syncthreads();
    if (tid == 0) __hip_atomic_store(&flags[w], t, __ATOMIC_RELAXED, __HIP_MEMORY_SCOPE_AGENT);
  }
}

// ---------------------------------------------------------------------------
// ctx[b,t,:] = sum_{i<15, t-i>=0} attn[b,t,i]*enc_out[b,t-i,:], attn via interleave gather.
__global__ __launch_bounds__(256)
void ctx_k(const float* __restrict__ smatt, const unsigned short* __restrict__ enc_out,
           unsigned short* __restrict__ ctx)
{
  const int bt = blockIdx.x;
  const int b = bt >> 9, t = bt & 511;
  __shared__ float a[15];
  const int tid = threadIdx.x;
  if (tid < 15){
    int q = 15*t + tid;
    a[tid] = smatt[(size_t)(q>>9)*M_ + b*T_ + (q&511)];
  }
  __syncthreads();
  const int j0 = tid*2;
  float s0=0.f, s1=0.f;
  for (int i=0;i<15;i++){
    int tau = t - i;
    if (tau < 0) break;
    unsigned int pr = *(const unsigned int*)(enc_out + ((size_t)(b*512+tau))*512 + j0);
    float wv = a[i];
    s0 = fmaf(wv, bf2f((unsigned short)(pr & 0xffff)), s0);
    s1 = fmaf(wv, bf2f((unsigned short)(pr >> 16)), s1);
  }
  unsigned int o = (unsigned int)f2bf(s0) | ((unsigned int)f2bf(s1)<<16);
  *(unsigned int*)(ctx + (size_t)bt*512 + j0) = o;
}

// ---------------------------------------------------------------------------
// out = hid @ W2.T + b2  (N=7 skinny). One wave per row.
__global__ __launch_bounds__(256)
void out_k(const unsigned short* __restrict__ hid, const float* __restrict__ W2,
           const float* __restrict__ b2, float* __restrict__ out)
{
  __shared__ float w2s[7*512];
  const int tid = threadIdx.x;
  for (int i = tid; i < 7*512; i += 256) w2s[i] = W2[i];
  __syncthreads();
  const int wv = tid>>6, lane = tid&63;
  const int mrow = blockIdx.x*4 + wv;
  float hv[8];
  {
    const uint4 uu = *(const uint4*)(hid + (size_t)mrow*512 + lane*8);
    const unsigned int q[4] = {uu.x, uu.y, uu.z, uu.w};
    #pragma unroll
    for (int i=0;i<4;i++){
      hv[i*2]   = bf2f((unsigned short)(q[i] & 0xffff));
      hv[i*2+1] = bf2f((unsigned short)(q[i] >> 16));
    }
  }
  float s[7];
  #pragma unroll
  for (int o=0;o<7;o++){
    float acc = 0.f;
    #pragma unroll
    for (int j=0;j<8;j++) acc = fmaf(hv[j], w2s[o*512 + lane*8 + j], acc);
    #pragma unroll
    for (int d=1; d<64; d<<=1) acc += __shfl_xor(acc, d);
    s[o] = acc;
  }
  if (lane == 0){
    #pragma unroll
    for (int o=0;o<7;o++) out[(size_t)mrow*7 + o] = s[o] + b2[o];
  }
}

// ---------------------------------------------------------------------------
// Workspace layout (needs ~136 MiB)
#define OFF_SACC   0ULL          // 18*16384*4 = 1179648
#define OFF_SM     2097152ULL    // 21*16384*4 = 1376256
#define OFF_FLAGS  3670016ULL    // enc:+0, dec:+256
#define OFF_HBUF_E 4194304ULL    // 2*32*544*2 = 69632
#define OFF_HBUF_D 4325376ULL    // 69632
#define OFF_ENCOUT 5242880ULL    // 16 MiB bf16
#define OFF_CTX    23068672ULL   // 16 MiB bf16
#define OFF_XG     41943040ULL   // 64 MiB bf16 (16384x2048)
#define OFF_DECOUT 109051904ULL  // 16 MiB bf16
#define OFF_HID    125829120ULL  // 16 MiB bf16

extern "C" void kernel_launch(void* const* d_in, const int* in_sizes, int n_in,
                              void* d_out, int out_size, void* d_ws, size_t ws_size,
                              hipStream_t stream)
{
  const float* face  = (const float*)d_in[1];
  const float* audio = (const float*)d_in[2];
  const float* desc  = (const float*)d_in[3];
  const float* sit   = (const float*)d_in[4];
  const float* scene = (const float*)d_in[5];
  const float* text  = (const float*)d_in[6];
  const float* Wt  = (const float*)d_in[8];  const float* bt  = (const float*)d_in[9];
  const float* Wf  = (const float*)d_in[10]; const float* bfc = (const float*)d_in[11];
  const float* Wa  = (const float*)d_in[12]; const float* ba  = (const float*)d_in[13];
  const float* Wsc = (const float*)d_in[14]; const float* bsc = (const float*)d_in[15];
  const float* Wd  = (const float*)d_in[16]; const float* bd  = (const float*)d_in[17];
  const float* Wsi = (const float*)d_in[18]; const float* bsi = (const float*)d_in[19];
  const float* w_att = (const float*)d_in[20];
  const float* w_ut = (const float*)d_in[22];
  const float* w_uf = (const float*)d_in[24];
  const float* w_ua = (const float*)d_in[26];
  const float* enc_Wih = (const float*)d_in[28];
  const float* enc_Whh = (const float*)d_in[29];
  const float* enc_b   = (const float*)d_in[30];
  const float* dec_Wih = (const float*)d_in[31];
  const float* dec_Whh = (const float*)d_in[32];
  const float* dec_b   = (const float*)d_in[33];
  const float* dec_h0  = (const float*)d_in[34];
  const float* dec_c0  = (const float*)d_in[35];
  const float* W1 = (const float*)d_in[36]; const float* b1 = (const float*)d_in[37];
  const float* W2 = (const float*)d_in[38]; const float* b2 = (const float*)d_in[39];
  float* outp = (float*)d_out;

  char* ws = (char*)d_ws;
  float* sacc = (float*)(ws + OFF_SACC);
  float* sm   = (float*)(ws + OFF_SM);
  int* flagsE = (int*)(ws + OFF_FLAGS);
  int* flagsD = (int*)(ws + OFF_FLAGS + 256);
  unsigned short* hbe = (unsigned short*)(ws + OFF_HBUF_E);
  unsigned short* hbd = (unsigned short*)(ws + OFF_HBUF_D);
  unsigned short* enc_out = (unsigned short*)(ws + OFF_ENCOUT);
  unsigned short* ctx = (unsigned short*)(ws + OFF_CTX);
  unsigned short* xg  = (unsigned short*)(ws + OFF_XG);
  unsigned short* dec_out = (unsigned short*)(ws + OFF_DECOUT);
  unsigned short* hid = (unsigned short*)(ws + OFF_HID);
  const float* smu = sm + 15*M_;   // uni softmaxes

  hipMemsetAsync(ws + OFF_SACC, 0, 18*M_*4, stream);
  hipMemsetAsync(ws + OFF_FLAGS, 0, (size_t)(OFF_HBUF_D + 69632 - OFF_FLAGS), stream);

  dim3 blk(256);
  dim3 g1(4,128);
  const float* w1p = w_att; const float* w2p = w_att + 512;
  // feature order: 0=text 1=face 2=audio 3=scene 4=desc 5=sit
  gemm_k<0><<<g1, blk, 0, stream>>>(text,  Wt,  bt,  768,  sacc+0*M_,  sacc+1*M_,  sacc+2*M_,  w1p, w2p, w_ut, nullptr, 0);
  gemm_k<0><<<g1, blk, 0, stream>>>(face,  Wf,  bfc, 512,  sacc+3*M_,  sacc+4*M_,  sacc+5*M_,  w1p, w2p, w_uf, nullptr, 0);
  gemm_k<0><<<g1, blk, 0, stream>>>(audio, Wa,  ba,  128,  sacc+6*M_,  sacc+7*M_,  sacc+8*M_,  w1p, w2p, w_ua, nullptr, 0);
  gemm_k<0><<<g1, blk, 0, stream>>>(scene, Wsc, bsc, 2048, sacc+9*M_,  sacc+10*M_, sacc+11*M_, w1p, w2p, w_ut, nullptr, 0);
  gemm_k<0><<<g1, blk, 0, stream>>>(desc,  Wd,  bd,  768,  sacc+12*M_, sacc+13*M_, sacc+14*M_, w1p, w2p, w_uf, nullptr, 0);
  gemm_k<0><<<g1, blk, 0, stream>>>(sit,   Wsi, bsi, 768,  sacc+15*M_, sacc+16*M_, sacc+17*M_, w1p, w2p, w_ua, nullptr, 0);
  softmax_k<<<dim3(21*32), blk, 0, stream>>>(sacc, sm);
  init2_k<<<dim3(64), blk, 0, stream>>>(smu, dec_h0, hbe, hbd);
  lstm_k<true><<<dim3(NWG), dim3(128), 0, stream>>>(enc_Whh, enc_Wih, enc_b, smu,
                                                    nullptr, nullptr, hbe, flagsE, enc_out);
  ctx_k<<<dim3(M_), blk, 0, stream>>>(sm, enc_out, ctx);
  gemm_k<1><<<dim3(16,128), blk, 0, stream>>>(ctx, dec_Wih, dec_b, 512,
      nullptr,nullptr,nullptr,nullptr,nullptr,nullptr, xg, 2048);
  lstm_k<false><<<dim3(NWG), dim3(128), 0, stream>>>(dec_Whh, nullptr, nullptr, nullptr,
                                                     xg, dec_c0, hbd, flagsD, dec_out);
  gemm_k<2><<<dim3(4,128), blk, 0, stream>>>(dec_out, W1, b1, 512,
      nullptr,nullptr,nullptr,nullptr,nullptr,nullptr, hid, 512);
  out_k<<<dim3(M_/4), blk, 0, stream>>>(hid, W2, b2, outp);
  (void)in_sizes; (void)n_in; (void)out_size; (void)ws_size;
}

// Round 3
// 6200.826 us; speedup vs baseline: 2.5096x; 1.6082x over previous
//
#include <hip/hip_runtime.h>

// MovieNet: 6 proj GEMMs(+tanh+dot epilogue) -> 21 softmax -> enc LSTM (persistent)
// -> ctx -> dec xg GEMM -> dec LSTM (persistent) -> MLP.
// R3: LSTM handoff via raw inline-asm device-scope (sc1) loads/stores —
//     no __hip_atomic_* (suspected RMW/serialized codegen), no cache fences.
//     outbuf also sc1 write-through (kills cross-XCD dirty-line false sharing).

#define B_ 32
#define T_ 512
#define H_ 512
#define M_ (B_*T_)   // 16384
#define NWG 64       // persistent LSTM workgroups (each owns 8 hidden units)

typedef __attribute__((ext_vector_type(8))) short bf16x8;
typedef __attribute__((ext_vector_type(4))) float f32x4;

__device__ inline unsigned short f2bf(float f){
  unsigned int u = __builtin_bit_cast(unsigned int, f);
  u += 0x7fffu + ((u>>16)&1u);      // round-to-nearest-even
  return (unsigned short)(u>>16);
}
__device__ inline float bf2f(unsigned short s){
  unsigned int u = ((unsigned int)s)<<16;
  return __builtin_bit_cast(float, u);
}
__device__ inline float tanh_f(float x){
  float ax = fabsf(x);
  if (ax > 12.f) return (x>0.f)?1.f:-1.f;
  float e = __expf(2.f*ax);
  float t = (e-1.f)/(e+1.f);
  return (x>=0.f)? t : -t;
}
__device__ inline float sigm(float x){ return 1.f/(1.f+__expf(-x)); }

// Device-scope (MALL coherence point) raw memory ops. Plain VMEM, fully
// pipelined, bypass L1/L2 via sc1 — no atomic RMW path.
__device__ inline void st_u32_sc1(void* p, unsigned int v){
  asm volatile("global_store_dword %0, %1, off sc1" :: "v"(p), "v"(v) : "memory");
}
__device__ inline bf16x8 ld_b128_sc1(const void* p){
  bf16x8 r;
  asm volatile("global_load_dwordx4 %0, %1, off sc1" : "=v"(r) : "v"(p));
  return r;
}

// ---------------------------------------------------------------------------
// Tiled bf16 GEMM, 128x128 tile, BK=32, 256 thr (4 waves, 2x2 of 64x64).
// MODE 0: A=fp32 features, epilogue tanh(acc+bias) then dot with w1/w2/w3,
//         atomicAdd row partials into s1/s2/s3 (t_x never materialized).
// MODE 1: A=bf16, epilogue acc+bias -> bf16 store.
// MODE 2: A=bf16, epilogue relu(acc+bias) -> bf16 store.
template<int MODE>
__global__ __launch_bounds__(256)
void gemm_k(const void* __restrict__ Ap, const float* __restrict__ Bw,
            const float* __restrict__ bias, int K,
            float* __restrict__ s1, float* __restrict__ s2, float* __restrict__ s3,
            const float* __restrict__ w1, const float* __restrict__ w2, const float* __restrict__ w3,
            unsigned short* __restrict__ outp, int ldout)
{
  __shared__ short As[128*40];   // +8 pad elems per row: conflict-free b128 reads
  __shared__ short Bs[128*40];
  const int tid = threadIdx.x;
  const int cb = blockIdx.x, rb = blockIdx.y;
  const int lane = tid & 63, wv = tid >> 6;
  const int vm = wv & 1, vn = wv >> 1;
  const int r = tid >> 1;
  const int c0 = (tid & 1) << 4;

  f32x4 acc[4][4];
  const f32x4 zz = {0.f,0.f,0.f,0.f};
  #pragma unroll
  for (int i=0;i<4;i++)
    #pragma unroll
    for (int j=0;j<4;j++) acc[i][j] = zz;

  union { short s[16]; bf16x8 v[2]; } tmpu;

  for (int kb = 0; kb < K; kb += 32){
    if (MODE == 0){
      const float* A = (const float*)Ap + (size_t)(rb*128 + r)*K + kb + c0;
      #pragma unroll
      for (int q=0;q<4;q++){
        float4 vv = ((const float4*)A)[q];
        tmpu.s[q*4+0]=(short)f2bf(vv.x); tmpu.s[q*4+1]=(short)f2bf(vv.y);
        tmpu.s[q*4+2]=(short)f2bf(vv.z); tmpu.s[q*4+3]=(short)f2bf(vv.w);
      }
      *(bf16x8*)&As[r*40 + c0]   = tmpu.v[0];
      *(bf16x8*)&As[r*40 + c0+8] = tmpu.v[1];
    } else {
      const unsigned short* A = (const unsigned short*)Ap + (size_t)(rb*128 + r)*K + kb + c0;
      uint4 u0 = ((const uint4*)A)[0];
      uint4 u1 = ((const uint4*)A)[1];
      *(uint4*)&As[r*40 + c0]   = u0;
      *(uint4*)&As[r*40 + c0+8] = u1;
    }
    {
      const float* Bp = Bw + (size_t)(cb*128 + r)*K + kb + c0;
      #pragma unroll
      for (int q=0;q<4;q++){
        float4 vv = ((const float4*)Bp)[q];
        tmpu.s[q*4+0]=(short)f2bf(vv.x); tmpu.s[q*4+1]=(short)f2bf(vv.y);
        tmpu.s[q*4+2]=(short)f2bf(vv.z); tmpu.s[q*4+3]=(short)f2bf(vv.w);
      }
      *(bf16x8*)&Bs[r*40 + c0]   = tmpu.v[0];
      *(bf16x8*)&Bs[r*40 + c0+8] = tmpu.v[1];
    }
    __syncthreads();
    bf16x8 af[4], bfr[4];
    const int fo = ((lane>>4)<<3);
    #pragma unroll
    for (int i=0;i<4;i++) af[i]  = *(const bf16x8*)&As[(vm*64 + i*16 + (lane&15))*40 + fo];
    #pragma unroll
    for (int i=0;i<4;i++) bfr[i] = *(const bf16x8*)&Bs[(vn*64 + i*16 + (lane&15))*40 + fo];
    #pragma unroll
    for (int mt=0;mt<4;mt++)
      #pragma unroll
      for (int nt=0;nt<4;nt++)
        acc[mt][nt] = __builtin_amdgcn_mfma_f32_16x16x32_bf16(af[mt], bfr[nt], acc[mt][nt], 0,0,0);
    __syncthreads();
  }

  const int rowbase = rb*128 + vm*64;
  const int colbase = cb*128 + vn*64;
  if (MODE == 0){
    float bv[4], w1v[4], w2v[4], w3v[4];
    #pragma unroll
    for (int nt=0;nt<4;nt++){
      int c = colbase + nt*16 + (lane&15);
      bv[nt]=bias[c]; w1v[nt]=w1[c]; w2v[nt]=w2[c]; w3v[nt]=w3[c];
    }
    #pragma unroll
    for (int mt=0;mt<4;mt++){
      #pragma unroll
      for (int rr=0;rr<4;rr++){
        float d1=0.f,d2=0.f,d3=0.f;
        #pragma unroll
        for (int nt=0;nt<4;nt++){
          float tv = tanh_f(acc[mt][nt][rr] + bv[nt]);
          d1 = fmaf(tv, w1v[nt], d1);
          d2 = fmaf(tv, w2v[nt], d2);
          d3 = fmaf(tv, w3v[nt], d3);
        }
        #pragma unroll
        for (int m=1;m<16;m<<=1){
          d1 += __shfl_xor(d1, m);
          d2 += __shfl_xor(d2, m);
          d3 += __shfl_xor(d3, m);
        }
        if ((lane & 15) == 0){
          int row = rowbase + mt*16 + ((lane>>4)<<2) + rr;
          atomicAdd(&s1[row], d1);
          atomicAdd(&s2[row], d2);
          atomicAdd(&s3[row], d3);
        }
      }
    }
  } else {
    #pragma unroll
    for (int mt=0;mt<4;mt++){
      #pragma unroll
      for (int nt=0;nt<4;nt++){
        int c = colbase + nt*16 + (lane&15);
        float bb = bias[c];
        #pragma unroll
        for (int rr=0;rr<4;rr++){
          int row = rowbase + mt*16 + ((lane>>4)<<2) + rr;
          float vv = acc[mt][nt][rr] + bb;
          if (MODE == 2) vv = fmaxf(vv, 0.f);
          outp[(size_t)row*ldout + c] = f2bf(vv);
        }
      }
    }
  }
}

// ---------------------------------------------------------------------------
// 21 softmaxes over T per batch. Scalar biases omitted (softmax shift-invariant).
__global__ __launch_bounds__(256)
void softmax_k(const float* __restrict__ sacc, float* __restrict__ sm)
{
  const int u = blockIdx.x % 21, b = blockIdx.x / 21;
  const int tid = threadIdx.x;
  __shared__ float red[4], red2[4];
  float v0, v1;
  if (u < 15){
    const int pa[15] = {0,0,0,0,0,1,1,1,1,2,2,2,3,3,4};
    const int pb[15] = {2,1,3,4,5,2,3,4,5,3,4,5,4,5,5};
    const float* A  = sacc + (size_t)(pa[u]*3+0)*M_ + b*T_;
    const float* Bq = sacc + (size_t)(pb[u]*3+1)*M_ + b*T_;
    v0 = A[tid] + Bq[tid]; v1 = A[tid+256] + Bq[tid+256];
  } else {
    const float* A = sacc + (size_t)((u-15)*3+2)*M_ + b*T_;
    v0 = A[tid]; v1 = A[tid+256];
  }
  float mx = fmaxf(v0,v1);
  #pragma unroll
  for (int d=1;d<64;d<<=1) mx = fmaxf(mx, __shfl_xor(mx,d));
  if ((tid&63)==0) red[tid>>6]=mx;
  __syncthreads();
  mx = fmaxf(fmaxf(red[0],red[1]),fmaxf(red[2],red[3]));
  float e0 = __expf(v0-mx), e1 = __expf(v1-mx);
  float s = e0+e1;
  #pragma unroll
  for (int d=1;d<64;d<<=1) s += __shfl_xor(s,d);
  if ((tid&63)==0) red2[tid>>6]=s;
  __syncthreads();
  s = red2[0]+red2[1]+red2[2]+red2[3];
  float inv = 1.f/s;
  float* o = sm + (size_t)u*M_ + b*T_;
  o[tid] = e0*inv; o[tid+256] = e1*inv;
}

// ---------------------------------------------------------------------------
// Seed the LSTM exchange buffers: dec h0, enc enc_in[t=0] slots, const "1" slot.
// Normal stores: kernel-boundary release flushes to MALL before lstm_k starts.
__global__ __launch_bounds__(256)
void init2_k(const float* __restrict__ smu, const float* __restrict__ dh0,
             unsigned short* __restrict__ hbe, unsigned short* __restrict__ hbd)
{
  int gid = blockIdx.x*256 + threadIdx.x;  // 0..16383
  { int b = gid >> 9, j = gid & 511; hbd[b*544 + j] = f2bf(dh0[j]); }
  if (gid < 32*6){
    int b = gid / 6, k = gid % 6;
    hbe[b*544 + 512 + k] = f2bf(smu[b*T_ + k]);
  }
  if (gid < 64){
    int b = gid & 31, bufi = gid >> 5;
    hbe[bufi*(32*544) + b*544 + 518] = 0x3F80;  // 1.0 (bias lane)
  }
}

// ---------------------------------------------------------------------------
// Persistent LSTM. 64 WGs x 128 thr. WG w owns hidden [w*8, w*8+8).
// Gates for all 32 batches via MFMA: A = [h(512); enc_in(6); 1; pad] (K=544),
// B = W_hh rows (+Wih cols +bias col for enc), resident in VGPR fragments.
// h exchanged via double-buffered global hbuf with per-WG step flags.
// All cross-WG traffic: plain sc1 (device-scope) loads/stores via inline asm.
// Ordering: all threads s_waitcnt vmcnt(0) -> __syncthreads -> tid0 flag store.
// Invariant: flag=t implies that WG finished READING buf[(t-1)&1], so buffer
// reuse at t+1 is race-free.
template<bool ENC>
__global__ __launch_bounds__(128, 1)
void lstm_k(const float* __restrict__ Whh, const float* __restrict__ Wih,
            const float* __restrict__ bvec, const float* __restrict__ smu,
            const unsigned short* __restrict__ xg, const float* __restrict__ c0v,
            unsigned short* hbuf, int* flags, unsigned short* __restrict__ outbuf)
{
  const int w = blockIdx.x, tid = threadIdx.x;
  const int lane = tid & 63, v = tid >> 6;

  bf16x8 bfrag[17];
  {
    const int n = lane & 15;
    const int R = (n&3)*512 + w*8 + v*4 + (n>>2);  // gate (n&3), hidden w*8+v*4+(n>>2)
    const int kq0 = (lane>>4)<<3;
    for (int ks=0; ks<17; ks++){
      union { short s[8]; bf16x8 vv; } bu;
      for (int j=0;j<8;j++){
        int k = ks*32 + kq0 + j;
        float val = 0.f;
        if (k < 512) val = Whh[(size_t)R*512 + k];
        else if (ENC){
          if (k < 518) val = Wih[R*6 + (k-512)];
          else if (k == 518) val = bvec[R];
        }
        bu.s[j] = (short)f2bf(val);
      }
      bfrag[ks] = bu.vv;
    }
  }
  const int b = tid & 31, u = tid >> 5;
  const int j0 = w*8 + u*2;
  float c0 = ENC ? 0.f : c0v[j0];
  float c1 = ENC ? 0.f : c0v[j0+1];
  __shared__ float gl[32*33];
  const int m = lane & 15;
  const int kq = (lane>>4)<<3;

  for (int t = 1; t <= 512; t++){
    float xv0[4], xv1[4];
    if (!ENC){  // prefetch precomputed xg (independent of h -> hides latency)
      const size_t bx = ((size_t)(b*512 + (t-1)))*2048 + w*8;
      #pragma unroll
      for (int g=0; g<4; g++){
        unsigned int xw = *(const unsigned int*)(xg + bx + g*512 + u*2);
        xv0[g] = bf2f((unsigned short)(xw & 0xffff));
        xv1[g] = bf2f((unsigned short)(xw >> 16));
      }
    }
    {
      const int want = t-1;
      const int* fp = flags + (lane & (NWG-1));
      int f;
      do {
        asm volatile("global_load_dword %0, %1, off sc1\n\ts_waitcnt vmcnt(0)"
                     : "=v"(f) : "v"(fp) : "memory");
      } while (!__all(f >= want));
    }
    const unsigned short* hb = hbuf + ((t-1)&1)*(32*544);
    f32x4 acc0 = {0.f,0.f,0.f,0.f}, acc1 = {0.f,0.f,0.f,0.f};
    {
      bf16x8 af0[17], af1[17];
      #pragma unroll
      for (int ks=0; ks<17; ks++){
        af0[ks] = ld_b128_sc1(hb + (size_t)m*544 + ks*32 + kq);
        af1[ks] = ld_b128_sc1(hb + (size_t)(m+16)*544 + ks*32 + kq);
      }
      asm volatile("s_waitcnt vmcnt(0)" ::: "memory");
      #pragma unroll
      for (int ks=0; ks<17; ks++){   // register barrier: pin MFMA after waitcnt
        asm volatile("" : "+v"(af0[ks]));
        asm volatile("" : "+v"(af1[ks]));
      }
      #pragma unroll
      for (int ks=0; ks<17; ks++){
        acc0 = __builtin_amdgcn_mfma_f32_16x16x32_bf16(af0[ks], bfrag[ks], acc0, 0,0,0);
        acc1 = __builtin_amdgcn_mfma_f32_16x16x32_bf16(af1[ks], bfrag[ks], acc1, 0,0,0);
      }
    }
    {
      const int col = v*16 + (lane&15);
      const int qb = ((lane>>4)<<2);
      #pragma unroll
      for (int rr=0;rr<4;rr++) gl[col*33 + qb + rr] = acc0[rr];
      #pragma unroll
      for (int rr=0;rr<4;rr++) gl[col*33 + 16 + qb + rr] = acc1[rr];
    }
    __syncthreads();
    unsigned int hw;
    {
      float hn[2];
      #pragma unroll
      for (int e=0;e<2;e++){
        const int jl = u*2 + e;
        const int colb = (jl>>2)*16 + (jl&3)*4;
        float gi = gl[(colb+0)*33 + b];
        float gf = gl[(colb+1)*33 + b];
        float gg = gl[(colb+2)*33 + b];
        float go = gl[(colb+3)*33 + b];
        if (!ENC){
          gi += e?xv1[0]:xv0[0]; gf += e?xv1[1]:xv0[1];
          gg += e?xv1[2]:xv0[2]; go += e?xv1[3]:xv0[3];
        }
        float& cc = e ? c1 : c0;
        cc = sigm(gf)*cc + sigm(gi)*tanh_f(gg);
        hn[e] = sigm(go)*tanh_f(cc);
      }
      hw = (unsigned int)f2bf(hn[0]) | ((unsigned int)f2bf(hn[1])<<16);
    }
    unsigned short* hbw = hbuf + (t&1)*(32*544);
    st_u32_sc1(hbw + b*544 + j0, hw);
    st_u32_sc1(outbuf + ((size_t)(b*512 + (t-1)))*512 + j0, hw);
    if (ENC && w < 32 && tid < 3 && t < 512){
      // stage enc_in for step t+1 into the buffer being published this step
      int q0 = 6*t + tid*2, q1 = q0 + 1;
      unsigned int ev = (unsigned int)f2bf(smu[(size_t)(q0>>9)*M_ + w*T_ + (q0&511)])
                      | ((unsigned int)f2bf(smu[(size_t)(q1>>9)*M_ + w*T_ + (q1&511)])<<16);
      st_u32_sc1(hbw + w*544 + 512 + tid*2, ev);
    }
    // Drain this thread's sc1 stores to the MALL, then barrier so tid0's
    // flag publish covers the whole WG.
    asm volatile("s_waitcnt vmcnt(0)" ::: "memory");
    __syncthreads();
    if (tid == 0) st_u32_sc1(&flags[w], (unsigned int)t);
  }
}

// ---------------------------------------------------------------------------
// ctx[b,t,:] = sum_{i<15, t-i>=0} attn[b,t,i]*enc_out[b,t-i,:], attn via interleave gather.
__global__ __launch_bounds__(256)
void ctx_k(const float* __restrict__ smatt, const unsigned short* __restrict__ enc_out,
           unsigned short* __restrict__ ctx)
{
  const int bt = blockIdx.x;
  const int b = bt >> 9, t = bt & 511;
  __shared__ float a[15];
  const int tid = threadIdx.x;
  if (tid < 15){
    int q = 15*t + tid;
    a[tid] = smatt[(size_t)(q>>9)*M_ + b*T_ + (q&511)];
  }
  __syncthreads();
  const int j0 = tid*2;
  float s0=0.f, s1=0.f;
  for (int i=0;i<15;i++){
    int tau = t - i;
    if (tau < 0) break;
    unsigned int pr = *(const unsigned int*)(enc_out + ((size_t)(b*512+tau))*512 + j0);
    float wv = a[i];
    s0 = fmaf(wv, bf2f((unsigned short)(pr & 0xffff)), s0);
    s1 = fmaf(wv, bf2f((unsigned short)(pr >> 16)), s1);
  }
  unsigned int o = (unsigned int)f2bf(s0) | ((unsigned int)f2bf(s1)<<16);
  *(unsigned int*)(ctx + (size_t)bt*512 + j0) = o;
}

// ---------------------------------------------------------------------------
// out = hid @ W2.T + b2  (N=7 skinny). One wave per row.
__global__ __launch_bounds__(256)
void out_k(const unsigned short* __restrict__ hid, const float* __restrict__ W2,
           const float* __restrict__ b2, float* __restrict__ out)
{
  __shared__ float w2s[7*512];
  const int tid = threadIdx.x;
  for (int i = tid; i < 7*512; i += 256) w2s[i] = W2[i];
  __syncthreads();
  const int wv = tid>>6, lane = tid&63;
  const int mrow = blockIdx.x*4 + wv;
  float hv[8];
  {
    const uint4 uu = *(const uint4*)(hid + (size_t)mrow*512 + lane*8);
    const unsigned int q[4] = {uu.x, uu.y, uu.z, uu.w};
    #pragma unroll
    for (int i=0;i<4;i++){
      hv[i*2]   = bf2f((unsigned short)(q[i] & 0xffff));
      hv[i*2+1] = bf2f((unsigned short)(q[i] >> 16));
    }
  }
  float s[7];
  #pragma unroll
  for (int o=0;o<7;o++){
    float acc = 0.f;
    #pragma unroll
    for (int j=0;j<8;j++) acc = fmaf(hv[j], w2s[o*512 + lane*8 + j], acc);
    #pragma unroll
    for (int d=1; d<64; d<<=1) acc += __shfl_xor(acc, d);
    s[o] = acc;
  }
  if (lane == 0){
    #pragma unroll
    for (int o=0;o<7;o++) out[(size_t)mrow*7 + o] = s[o] + b2[o];
  }
}

// ---------------------------------------------------------------------------
// Workspace layout (needs ~136 MiB)
#define OFF_SACC   0ULL          // 18*16384*4 = 1179648
#define OFF_SM     2097152ULL    // 21*16384*4 = 1376256
#define OFF_FLAGS  3670016ULL    // enc:+0, dec:+256
#define OFF_HBUF_E 4194304ULL    // 2*32*544*2 = 69632
#define OFF_HBUF_D 4325376ULL    // 69632
#define OFF_ENCOUT 5242880ULL    // 16 MiB bf16
#define OFF_CTX    23068672ULL   // 16 MiB bf16
#define OFF_XG     41943040ULL   // 64 MiB bf16 (16384x2048)
#define OFF_DECOUT 109051904ULL  // 16 MiB bf16
#define OFF_HID    125829120ULL  // 16 MiB bf16

extern "C" void kernel_launch(void* const* d_in, const int* in_sizes, int n_in,
                              void* d_out, int out_size, void* d_ws, size_t ws_size,
                              hipStream_t stream)
{
  const float* face  = (const float*)d_in[1];
  const float* audio = (const float*)d_in[2];
  const float* desc  = (const float*)d_in[3];
  const float* sit   = (const float*)d_in[4];
  const float* scene = (const float*)d_in[5];
  const float* text  = (const float*)d_in[6];
  const float* Wt  = (const float*)d_in[8];  const float* bt  = (const float*)d_in[9];
  const float* Wf  = (const float*)d_in[10]; const float* bfc = (const float*)d_in[11];
  const float* Wa  = (const float*)d_in[12]; const float* ba  = (const float*)d_in[13];
  const float* Wsc = (const float*)d_in[14]; const float* bsc = (const float*)d_in[15];
  const float* Wd  = (const float*)d_in[16]; const float* bd  = (const float*)d_in[17];
  const float* Wsi = (const float*)d_in[18]; const float* bsi = (const float*)d_in[19];
  const float* w_att = (const float*)d_in[20];
  const float* w_ut = (const float*)d_in[22];
  const float* w_uf = (const float*)d_in[24];
  const float* w_ua = (const float*)d_in[26];
  const float* enc_Wih = (const float*)d_in[28];
  const float* enc_Whh = (const float*)d_in[29];
  const float* enc_b   = (const float*)d_in[30];
  const float* dec_Wih = (const float*)d_in[31];
  const float* dec_Whh = (const float*)d_in[32];
  const float* dec_b   = (const float*)d_in[33];
  const float* dec_h0  = (const float*)d_in[34];
  const float* dec_c0  = (const float*)d_in[35];
  const float* W1 = (const float*)d_in[36]; const float* b1 = (const float*)d_in[37];
  const float* W2 = (const float*)d_in[38]; const float* b2 = (const float*)d_in[39];
  float* outp = (float*)d_out;

  char* ws = (char*)d_ws;
  float* sacc = (float*)(ws + OFF_SACC);
  float* sm   = (float*)(ws + OFF_SM);
  int* flagsE = (int*)(ws + OFF_FLAGS);
  int* flagsD = (int*)(ws + OFF_FLAGS + 256);
  unsigned short* hbe = (unsigned short*)(ws + OFF_HBUF_E);
  unsigned short* hbd = (unsigned short*)(ws + OFF_HBUF_D);
  unsigned short* enc_out = (unsigned short*)(ws + OFF_ENCOUT);
  unsigned short* ctx = (unsigned short*)(ws + OFF_CTX);
  unsigned short* xg  = (unsigned short*)(ws + OFF_XG);
  unsigned short* dec_out = (unsigned short*)(ws + OFF_DECOUT);
  unsigned short* hid = (unsigned short*)(ws + OFF_HID);
  const float* smu = sm + 15*M_;   // uni softmaxes

  hipMemsetAsync(ws + OFF_SACC, 0, 18*M_*4, stream);
  hipMemsetAsync(ws + OFF_FLAGS, 0, (size_t)(OFF_HBUF_D + 69632 - OFF_FLAGS), stream);

  dim3 blk(256);
  dim3 g1(4,128);
  const float* w1p = w_att; const float* w2p = w_att + 512;
  // feature order: 0=text 1=face 2=audio 3=scene 4=desc 5=sit
  gemm_k<0><<<g1, blk, 0, stream>>>(text,  Wt,  bt,  768,  sacc+0*M_,  sacc+1*M_,  sacc+2*M_,  w1p, w2p, w_ut, nullptr, 0);
  gemm_k<0><<<g1, blk, 0, stream>>>(face,  Wf,  bfc, 512,  sacc+3*M_,  sacc+4*M_,  sacc+5*M_,  w1p, w2p, w_uf, nullptr, 0);
  gemm_k<0><<<g1, blk, 0, stream>>>(audio, Wa,  ba,  128,  sacc+6*M_,  sacc+7*M_,  sacc+8*M_,  w1p, w2p, w_ua, nullptr, 0);
  gemm_k<0><<<g1, blk, 0, stream>>>(scene, Wsc, bsc, 2048, sacc+9*M_,  sacc+10*M_, sacc+11*M_, w1p, w2p, w_ut, nullptr, 0);
  gemm_k<0><<<g1, blk, 0, stream>>>(desc,  Wd,  bd,  768,  sacc+12*M_, sacc+13*M_, sacc+14*M_, w1p, w2p, w_uf, nullptr, 0);
  gemm_k<0><<<g1, blk, 0, stream>>>(sit,   Wsi, bsi, 768,  sacc+15*M_, sacc+16*M_, sacc+17*M_, w1p, w2p, w_ua, nullptr, 0);
  softmax_k<<<dim3(21*32), blk, 0, stream>>>(sacc, sm);
  init2_k<<<dim3(64), blk, 0, stream>>>(smu, dec_h0, hbe, hbd);
  lstm_k<true><<<dim3(NWG), dim3(128), 0, stream>>>(enc_Whh, enc_Wih, enc_b, smu,
                                                    nullptr, nullptr, hbe, flagsE, enc_out);
  ctx_k<<<dim3(M_), blk, 0, stream>>>(sm, enc_out, ctx);
  gemm_k<1><<<dim3(16,128), blk, 0, stream>>>(ctx, dec_Wih, dec_b, 512,
      nullptr,nullptr,nullptr,nullptr,nullptr,nullptr, xg, 2048);
  lstm_k<false><<<dim3(NWG), dim3(128), 0, stream>>>(dec_Whh, nullptr, nullptr, nullptr,
                                                     xg, dec_c0, hbd, flagsD, dec_out);
  gemm_k<2><<<dim3(4,128), blk, 0, stream>>>(dec_out, W1, b1, 512,
      nullptr,nullptr,nullptr,nullptr,nullptr,nullptr, hid, 512);
  out_k<<<dim3(M_/4), blk, 0, stream>>>(hid, W2, b2, outp);
  (void)in_sizes; (void)n_in; (void)out_size; (void)ws_size;
}